// Round 12
// baseline (239.318 us; speedup 1.0000x reference)
//
#include <hip/hip_runtime.h>
#include <hip/hip_bf16.h>

typedef __hip_bfloat16 bf16;
typedef unsigned int u32;
typedef unsigned short u16;
typedef __attribute__((ext_vector_type(8))) short bf16x8;
typedef __attribute__((ext_vector_type(4))) float f32x4;

constexpr int N   = 50000;
constexpr int E   = 1600000;
constexpr int C   = 128;             // channels (H * 32)
constexpr int H   = 4;               // heads
constexpr int NB  = 782;             // dst buckets of 64 nodes (782*64 >= 50000)
constexpr int CAP = 2560;            // LDS staging capacity per bucket in kfill2
constexpr int NCH = 256;             // chunks (bin-count blocks)
constexpr int CHUNK = E / NCH;       // 6250 edges per chunk (exact)
constexpr int WT_COLS = 144;         // 128 h-cols + 8 att-proj cols + 8 zero pad
constexpr float NEG  = 0.2f;
constexpr float SEPS = 1e-16f;
constexpr float LEPS = 1e-5f;

__device__ __forceinline__ float lo16(u32 v) { return __uint_as_float(v << 16); }
__device__ __forceinline__ float hi16(u32 v) { return __uint_as_float(v & 0xFFFF0000u); }
__device__ __forceinline__ u16 bfbits(float f) {
    __hip_bfloat16 h = __float2bfloat16(f);
    return *reinterpret_cast<u16*>(&h);
}

// K0 v2: wt[c][k] split-bf16; c in [0,128) = W cols; [128,136) = attention
// projection cols (W@att_s, W@att_d per head); [136,144) = zero pad.
__global__ __launch_bounds__(256) void k0_wprep(
    const float* __restrict__ W,
    const float* __restrict__ att_s, const float* __restrict__ att_d,
    u16* __restrict__ wt_hi, u16* __restrict__ wt_lo)
{
    const int i = blockIdx.x * 256 + threadIdx.x;   // 72 blocks: 144*128 entries
    if (i >= WT_COLS * 128) return;
    const int c = i >> 7, k = i & 127;
    float w = 0.f;
    if (c < 128) {
        w = W[k * 128 + c];
    } else if (c < 136) {
        const int vc = c - 128;
        const int h = vc & 3;
        const float* att = (vc < 4) ? att_s : att_d;
        float s = 0.f;
#pragma unroll
        for (int j = 0; j < 32; ++j)
            s = fmaf(W[k * 128 + h * 32 + j], att[h * 32 + j], s);
        w = s;
    }
    const __hip_bfloat16 h = __float2bfloat16(w);
    const float fh = __bfloat162float(h);
    wt_hi[i] = *(const u16*)&h;
    wt_lo[i] = bfbits(w - fh);
}

// KG v3: 128 rows/block (391 blocks, 4 waves, 32 rows/wave = 2 row-groups).
// ks-outer, B double-buffered in registers: 18 B-loads of ks+1 batch-issued
// (fenced) before ks's 54 MFMAs -> L2 latency hidden under MFMA work; each
// B element now feeds 6 MFMAs (was 3). ~200 VGPR by design (ILP over TLP —
// R11: at VGPR 60 the B-loads serialized into ~36 L2 round-trips/wave).
// Numerically bit-identical: same per-output MFMA sequence and ks order.
__global__ __launch_bounds__(256, 2) void kg_gemm(
    const float* __restrict__ x,
    const u16* __restrict__ wt_hi, const u16* __restrict__ wt_lo,
    u16* __restrict__ hb, float* __restrict__ as_, float* __restrict__ ad_)
{
    const int t    = threadIdx.x;
    const int m0   = (int)blockIdx.x * 128;
    const int lane = t & 63;
    const int w    = t >> 6;                  // wave id: rows [w*32, w*32+32)
    const int bcol = lane & 15;               // A row within group / B col / C col
    const int akg  = lane >> 4;               // k-group 0..3 / C row quarter

    const int r0 = min(m0 + w * 32 + bcol,      N - 1);
    const int r1 = min(m0 + w * 32 + 16 + bcol, N - 1);
    const float* x0 = x + (size_t)r0 * 128 + akg * 8;
    const float* x1 = x + (size_t)r1 * 128 + akg * 8;

    // batch-issue all 16 x loads (cold HBM) first
    float4 q[16];
#pragma unroll
    for (int ks = 0; ks < 4; ++ks) {
        q[4 * ks + 0] = *(const float4*)(x0 + ks * 32);
        q[4 * ks + 1] = *(const float4*)(x0 + ks * 32 + 4);
        q[4 * ks + 2] = *(const float4*)(x1 + ks * 32);
        q[4 * ks + 3] = *(const float4*)(x1 + ks * 32 + 4);
    }
    __builtin_amdgcn_sched_barrier(0);

    const u16* bp = wt_hi + bcol * 128 + akg * 8;
    const u16* bq = wt_lo + bcol * 128 + akg * 8;
    bf16x8 BhA[9], BlA[9], BhB[9], BlB[9];

#define LOADB(BH, BL, ks)                                           \
    _Pragma("unroll")                                               \
    for (int nt = 0; nt < 9; ++nt) {                                \
        BH[nt] = *(const bf16x8*)(bp + nt * 2048 + (ks) * 32);      \
        BL[nt] = *(const bf16x8*)(bq + nt * 2048 + (ks) * 32);      \
    }

    LOADB(BhA, BlA, 0)
    __builtin_amdgcn_sched_barrier(0);

    // convert x -> A fragments (drains the x loads; B0 stays in flight)
    bf16x8 Ah[2][4], Al[2][4];
#pragma unroll
    for (int ks = 0; ks < 4; ++ks) {
#pragma unroll
        for (int rg = 0; rg < 2; ++rg) {
            const float4 qa = q[4 * ks + 2 * rg];
            const float4 qb = q[4 * ks + 2 * rg + 1];
            const float f[8] = {qa.x, qa.y, qa.z, qa.w, qb.x, qb.y, qb.z, qb.w};
#pragma unroll
            for (int j = 0; j < 8; ++j) {
                const __hip_bfloat16 hh = __float2bfloat16(f[j]);
                Ah[rg][ks][j] = *(const short*)&hh;
                const __hip_bfloat16 hl = __float2bfloat16(f[j] - __bfloat162float(hh));
                Al[rg][ks][j] = *(const short*)&hl;
            }
        }
    }

    f32x4 acc[2][9];
#pragma unroll
    for (int rg = 0; rg < 2; ++rg)
#pragma unroll
        for (int nt = 0; nt < 9; ++nt) acc[rg][nt] = f32x4{0.f, 0.f, 0.f, 0.f};

#define STEP(BHc, BLc, ks)                                          \
    _Pragma("unroll")                                               \
    for (int rg = 0; rg < 2; ++rg) {                                \
        _Pragma("unroll")                                           \
        for (int nt = 0; nt < 9; ++nt) {                            \
            acc[rg][nt] = __builtin_amdgcn_mfma_f32_16x16x32_bf16(Ah[rg][ks], BHc[nt], acc[rg][nt], 0, 0, 0); \
            acc[rg][nt] = __builtin_amdgcn_mfma_f32_16x16x32_bf16(Al[rg][ks], BHc[nt], acc[rg][nt], 0, 0, 0); \
            acc[rg][nt] = __builtin_amdgcn_mfma_f32_16x16x32_bf16(Ah[rg][ks], BLc[nt], acc[rg][nt], 0, 0, 0); \
        }                                                           \
    }

    LOADB(BhB, BlB, 1)
    __builtin_amdgcn_sched_barrier(0);
    STEP(BhA, BlA, 0)
    LOADB(BhA, BlA, 2)
    __builtin_amdgcn_sched_barrier(0);
    STEP(BhB, BlB, 1)
    LOADB(BhB, BlB, 3)
    __builtin_amdgcn_sched_barrier(0);
    STEP(BhA, BlA, 2)
    STEP(BhB, BlB, 3)

#undef STEP
#undef LOADB

    // hb store: C/D layout col=lane&15, row=(lane>>4)*4+reg  [m89/m91]
#pragma unroll
    for (int rg = 0; rg < 2; ++rg) {
#pragma unroll
        for (int nt = 0; nt < 8; ++nt) {
            const int ch = nt * 16 + bcol;
#pragma unroll
            for (int r = 0; r < 4; ++r) {
                const int node = m0 + w * 32 + rg * 16 + akg * 4 + r;
                if (node < N) hb[(size_t)node * 128 + ch] = bfbits(acc[rg][nt][r]);
            }
        }
        // attention projections: tile 8 (cols 0-3: as head, 4-7: ad head)
        if (bcol < 8) {
            float* dst = (bcol < 4) ? (as_ + bcol) : (ad_ + (bcol - 4));
#pragma unroll
            for (int r = 0; r < 4; ++r) {
                const int node = m0 + w * 32 + rg * 16 + akg * 4 + r;
                if (node < N) dst[(size_t)node * H] = acc[rg][8][r];
            }
        }
    }
}

// KC: per-chunk dst-bucket counts (unchanged — control).
__global__ __launch_bounds__(256) void kc_count(
    const int* __restrict__ ei, u32* __restrict__ gcnt)
{
    __shared__ u32 lcnt[NB];
    const int t = threadIdx.x;
    const int c = blockIdx.x;
    const int base = c * CHUNK;
    for (int i = t; i < NB; i += 256) lcnt[i] = 0;
    __syncthreads();
    for (int i = t; i < CHUNK; i += 256)
        atomicAdd(&lcnt[((u32)ei[E + base + i]) >> 6], 1u);
    __syncthreads();
    for (int i = t; i < NB; i += 256) gcnt[i * NCH + c] = lcnt[i];
}

// S2A (unchanged — control): per-bucket scan over chunks.
__global__ __launch_bounds__(256) void s2a_scan(
    const u32* __restrict__ gcnt, u32* __restrict__ gbase, u32* __restrict__ tot)
{
    __shared__ u32 wsum[4];
    const int b = blockIdx.x, t = threadIdx.x, lane = t & 63, w = t >> 6;
    const u32 v = gcnt[b * NCH + t];
    u32 incl = v;
#pragma unroll
    for (int off = 1; off < 64; off <<= 1) {
        u32 u = __shfl_up(incl, off, 64);
        if (lane >= off) incl += u;
    }
    if (lane == 63) wsum[w] = incl;
    __syncthreads();
    u32 wpre = 0;
#pragma unroll
    for (int i = 0; i < 4; ++i) if (i < w) wpre += wsum[i];
    gbase[b * NCH + t] = wpre + incl - v;
    if (t == 255) tot[b] = wpre + incl;
}

// S2B (unchanged — control): exclusive scan of tot -> bbase.
__global__ __launch_bounds__(64) void s2b_scan(
    const u32* __restrict__ tot, u32* __restrict__ bbase)
{
    const int t = threadIdx.x;
    u32 vals[13];
    u32 s = 0;
#pragma unroll
    for (int i = 0; i < 13; ++i) {
        int idx = t * 13 + i;
        u32 v = (idx < NB) ? tot[idx] : 0u;
        vals[i] = s; s += v;
    }
    u32 incl = s;
#pragma unroll
    for (int off = 1; off < 64; off <<= 1) {
        u32 u = __shfl_up(incl, off, 64);
        if (t >= off) incl += u;
    }
    const u32 excl = incl - s;
#pragma unroll
    for (int i = 0; i < 13; ++i) {
        int idx = t * 13 + i;
        if (idx < NB) bbase[idx] = excl + vals[i];
    }
}

// KBINB v2 (unchanged — control).
__global__ __launch_bounds__(256) void kbinB(
    const int* __restrict__ ei, const u32* __restrict__ gbase,
    const u32* __restrict__ bbase, u32* __restrict__ pairs)
{
    __shared__ u32 sl[NB];
    __shared__ u32 lfill[NB];
    const int t = threadIdx.x;
    const int c = blockIdx.x;

    for (int i = t; i < NB; i += 256) {
        sl[i] = bbase[i] + gbase[(size_t)i * NCH + c];
        lfill[i] = 0u;
    }
    __syncthreads();

    const int base = c * CHUNK;
    for (int i = t; i < CHUNK; i += 256) {
        const u32 src = (u32)ei[base + i];
        const u32 dst = (u32)ei[E + base + i];
        const u32 b = dst >> 6;
        const u32 pos = atomicAdd(&lfill[b], 1u);
        pairs[sl[b] + pos] = src | ((dst & 63u) << 16);
    }
}

// KFILL2 v2 (unchanged — control).
__global__ __launch_bounds__(256) void kfill2(
    const u32* __restrict__ pairs, const u32* __restrict__ tot,
    const u32* __restrict__ bbase, int* __restrict__ row_ptr, u16* __restrict__ col)
{
    __shared__ u32 spr[CAP];
    __shared__ u16 scol[CAP];
    __shared__ int jcnt[64], joff[64], jcur[64];
    const int b = blockIdx.x, t = threadIdx.x;
    const int base = (int)bbase[b];
    const int cntb = (int)tot[b];
    if (t < 64) jcnt[t] = 0;
    __syncthreads();

    const u32* pr = pairs + base;
    for (int i = t; i < cntb; i += 256) spr[i] = pr[i];
    __syncthreads();
    for (int i = t; i < cntb; i += 256) atomicAdd(&jcnt[spr[i] >> 16], 1);
    __syncthreads();
    if (t < 64) {
        int v = jcnt[t], incl = v;
#pragma unroll
        for (int off = 1; off < 64; off <<= 1) {
            int u = __shfl_up(incl, off, 64);
            if (t >= off) incl += u;
        }
        joff[t] = incl - v;
        const int n = b * 64 + t;
        if (n < N) row_ptr[n] = base + joff[t];
        jcur[t] = 0;
    }
    __syncthreads();
    for (int i = t; i < cntb; i += 256) {
        const u32 p = spr[i];
        const int j = p >> 16;
        const int pos = atomicAdd(&jcur[j], 1);
        scol[joff[j] + pos] = (u16)(p & 0xFFFFu);
    }
    __syncthreads();
    for (int i = t; i < cntb; i += 256) col[base + i] = scol[i];
    if (b == 0 && t == 0) row_ptr[N] = E;
}

// KD v4 (unchanged — control), two half-dispatches via n0 offset.
__global__ __launch_bounds__(256) void kd_agg_ln(
    const int* __restrict__ row_ptr, const u16* __restrict__ col,
    const u32* __restrict__ hb, const float* __restrict__ as_,
    const float* __restrict__ ad_,
    const float* __restrict__ bias, const float* __restrict__ gamma,
    const float* __restrict__ beta, float* __restrict__ out, int n0)
{
    __shared__ float wlds[4][64];
    const int tid  = threadIdx.x;
    const int lane = tid & 63;
    const int wv   = __builtin_amdgcn_readfirstlane(tid >> 6);
    const int n    = __builtin_amdgcn_readfirstlane(n0 + (int)blockIdx.x * 4 + (tid >> 6));
    if (n >= N) return;

    const int head  = lane >> 4;
    const int eoff  = lane & 15;
    const int wbase = head << 4;
    float* __restrict__ wrow = wlds[wv];

    const float adn = ad_[n * H + head];
    const float asn = as_[n * H + head];

    float ls = asn + adn;
    ls = fmaxf(ls, NEG * ls);
    const float wself = __expf(ls);
    float den = (eoff == 0) ? wself : 0.f;
    const u32 hvs = hb[n * 64 + lane];
    float num0 = wself * lo16(hvs);
    float num1 = wself * hi16(hvs);

    const int k0  = row_ptr[n];
    const int deg = row_ptr[n + 1] - k0;
    const int ntiles = (deg + 15) >> 4;

    const int cnt0 = deg < 16 ? deg : 16;
    const int cnt1 = (deg - 16) < 16 ? (deg - 16) : 16;
    int colv_cur = (eoff < cnt0) ? (int)col[k0 + eoff]      : 0;
    int colv_nxt = (eoff < cnt1) ? (int)col[k0 + 16 + eoff] : 0;
    float a_cur  = as_[colv_cur * H + head];
    int cntc = cnt0, cntn = cnt1;

    int k = k0;
    for (int t = 0; t < ntiles; ++t, k += 16) {
        const int rem2 = deg - 16 * (t + 2);
        const int cnt2 = rem2 < 16 ? rem2 : 16;
        const int cf_raw = (int)col[k + 32 + eoff];
        const int colv_f = (eoff < cnt2) ? cf_raw : 0;

        float le = a_cur + adn;
        le = fmaxf(le, NEG * le);
        const float w = (eoff < cntc) ? __expf(le) : 0.f;
        den += w;
        wrow[lane] = w;
        const int colc = colv_cur;

#define GL(i) const u32* rp##i = hb + ((size_t)(u32)__builtin_amdgcn_readlane(colc, i) << 6); \
              const u32 v##i = rp##i[lane];
        GL(0) GL(1) GL(2) GL(3) GL(4) GL(5) GL(6) GL(7)
        GL(8) GL(9) GL(10) GL(11) GL(12) GL(13) GL(14) GL(15)
#undef GL
        __builtin_amdgcn_sched_barrier(0);

        const float a_n = as_[colv_nxt * H + head];
        __builtin_amdgcn_sched_barrier(0);

        {
            const float4 wa = *(const float4*)(wrow + wbase + 0);
            num0 = fmaf(wa.x, lo16(v0), num0);  num1 = fmaf(wa.x, hi16(v0), num1);
            num0 = fmaf(wa.y, lo16(v1), num0);  num1 = fmaf(wa.y, hi16(v1), num1);
            num0 = fmaf(wa.z, lo16(v2), num0);  num1 = fmaf(wa.z, hi16(v2), num1);
            num0 = fmaf(wa.w, lo16(v3), num0);  num1 = fmaf(wa.w, hi16(v3), num1);
            const float4 wb = *(const float4*)(wrow + wbase + 4);
            num0 = fmaf(wb.x, lo16(v4), num0);  num1 = fmaf(wb.x, hi16(v4), num1);
            num0 = fmaf(wb.y, lo16(v5), num0);  num1 = fmaf(wb.y, hi16(v5), num1);
            num0 = fmaf(wb.z, lo16(v6), num0);  num1 = fmaf(wb.z, hi16(v6), num1);
            num0 = fmaf(wb.w, lo16(v7), num0);  num1 = fmaf(wb.w, hi16(v7), num1);
            const float4 wc = *(const float4*)(wrow + wbase + 8);
            num0 = fmaf(wc.x, lo16(v8), num0);  num1 = fmaf(wc.x, hi16(v8), num1);
            num0 = fmaf(wc.y, lo16(v9), num0);  num1 = fmaf(wc.y, hi16(v9), num1);
            num0 = fmaf(wc.z, lo16(v10), num0); num1 = fmaf(wc.z, hi16(v10), num1);
            num0 = fmaf(wc.w, lo16(v11), num0); num1 = fmaf(wc.w, hi16(v11), num1);
            const float4 wd = *(const float4*)(wrow + wbase + 12);
            num0 = fmaf(wd.x, lo16(v12), num0); num1 = fmaf(wd.x, hi16(v12), num1);
            num0 = fmaf(wd.y, lo16(v13), num0); num1 = fmaf(wd.y, hi16(v13), num1);
            num0 = fmaf(wd.z, lo16(v14), num0); num1 = fmaf(wd.z, hi16(v14), num1);
            num0 = fmaf(wd.w, lo16(v15), num0); num1 = fmaf(wd.w, hi16(v15), num1);
        }

        colv_cur = colv_nxt; colv_nxt = colv_f;
        a_cur = a_n;
        cntc = cntn; cntn = cnt2;
    }

#pragma unroll
    for (int off = 1; off < 16; off <<= 1) den += __shfl_xor(den, off, 64);

    const int c0 = lane * 2;
    const float inv_den = 1.f / (den + SEPS);
    const float2 bi = *(const float2*)(bias + c0);
    float v0 = num0 * inv_den + bi.x;
    float v1 = num1 * inv_den + bi.y;

    float sum = v0 + v1;
#pragma unroll
    for (int off = 32; off; off >>= 1) sum += __shfl_xor(sum, off, 64);
    const float mu = sum * (1.0f / C);
    const float d0 = v0 - mu, d1 = v1 - mu;
    float sq = d0 * d0 + d1 * d1;
#pragma unroll
    for (int off = 32; off; off >>= 1) sq += __shfl_xor(sq, off, 64);
    const float inv = rsqrtf(sq * (1.0f / C) + LEPS);
    const float2 ga = *(const float2*)(gamma + c0);
    const float2 be = *(const float2*)(beta  + c0);
    float y0 = d0 * inv * ga.x + be.x;
    float y1 = d1 * inv * ga.y + be.y;
    y0 = y0 > 0.f ? y0 : __expf(y0) - 1.f;
    y1 = y1 > 0.f ? y1 : __expf(y1) - 1.f;
    float2 o; o.x = y0; o.y = y1;
    *(float2*)(out + (size_t)n * C + c0) = o;
}

extern "C" void kernel_launch(void* const* d_in, const int* in_sizes, int n_in,
                              void* d_out, int out_size, void* d_ws, size_t ws_size,
                              hipStream_t stream)
{
    const float* x     = (const float*)d_in[0];
    const int*   ei    = (const int*)  d_in[1];
    const float* W     = (const float*)d_in[2];
    const float* att_s = (const float*)d_in[3];
    const float* att_d = (const float*)d_in[4];
    const float* bias  = (const float*)d_in[5];
    const float* gamma = (const float*)d_in[6];
    const float* beta  = (const float*)d_in[7];
    float* out = (float*)d_out;

    // ws (~26 MB): hb | as_ | ad_ | pairs | col | row_ptr | gcnt | gbase
    //            | tot | bbase | wt_hi | wt_lo
    char* p = (char*)d_ws;
    bf16*  hb      = (bf16*)p;   p += (size_t)N * C * sizeof(bf16);
    float* as_     = (float*)p;  p += (size_t)N * H * sizeof(float);
    float* ad_     = (float*)p;  p += (size_t)N * H * sizeof(float);
    u32*   pairs   = (u32*)p;    p += (size_t)E * sizeof(u32);
    u16*   col     = (u16*)p;    p += ((size_t)(E + 64) * sizeof(u16) + 15) & ~(size_t)15;
    int*   row_ptr = (int*)p;    p += ((size_t)(N + 1) * sizeof(int) + 15) & ~(size_t)15;
    u32*   gcnt    = (u32*)p;    p += (size_t)NB * NCH * sizeof(u32);
    u32*   gbase   = (u32*)p;    p += (size_t)NB * NCH * sizeof(u32);
    u32*   tot     = (u32*)p;    p += (((size_t)NB * sizeof(u32)) + 15) & ~(size_t)15;
    u32*   bbase   = (u32*)p;    p += (((size_t)NB * sizeof(u32)) + 15) & ~(size_t)15;
    u16*   wt_hi   = (u16*)p;    p += (size_t)WT_COLS * 128 * sizeof(u16);
    u16*   wt_lo   = (u16*)p;

    k0_wprep<<<(WT_COLS * 128 + 255) / 256, 256, 0, stream>>>(W, att_s, att_d, wt_hi, wt_lo);
    kg_gemm<<<(N + 127) / 128, 256, 0, stream>>>(x, wt_hi, wt_lo, (u16*)hb, as_, ad_);
    kc_count<<<NCH, 256, 0, stream>>>(ei, gcnt);
    s2a_scan<<<NB, 256, 0, stream>>>(gcnt, gbase, tot);
    s2b_scan<<<1, 64, 0, stream>>>(tot, bbase);
    kbinB<<<NCH, 256, 0, stream>>>(ei, gbase, bbase, pairs);
    kfill2<<<NB, 256, 0, stream>>>(pairs, tot, bbase, row_ptr, col);
    kd_agg_ln<<<(25000 * 64) / 256, 256, 0, stream>>>(
        row_ptr, col, (const u32*)hb, as_, ad_, bias, gamma, beta, out, 0);
    kd_agg_ln<<<(25000 * 64) / 256, 256, 0, stream>>>(
        row_ptr, col, (const u32*)hb, as_, ad_, bias, gamma, beta, out, 25000);
}

// Round 14
// 208.640 us; speedup vs baseline: 1.1470x; 1.1470x over previous
//
#include <hip/hip_runtime.h>
#include <hip/hip_bf16.h>

typedef __hip_bfloat16 bf16;
typedef unsigned int u32;
typedef unsigned short u16;
typedef __attribute__((ext_vector_type(8))) short bf16x8;
typedef __attribute__((ext_vector_type(4))) float f32x4;

constexpr int N   = 50000;
constexpr int E   = 1600000;
constexpr int C   = 128;             // channels (H * 32)
constexpr int H   = 4;               // heads
constexpr int NB  = 782;             // dst buckets of 64 nodes (782*64 >= 50000)
constexpr int CAP = 2560;            // LDS staging capacity per bucket in kfill2
constexpr int NCH = 256;             // chunks (bin-count blocks)
constexpr int CHUNK = E / NCH;       // 6250 edges per chunk (exact)
constexpr int WT_COLS = 144;         // 128 h-cols + 8 att-proj cols + 8 zero pad
constexpr float NEG  = 0.2f;
constexpr float SEPS = 1e-16f;
constexpr float LEPS = 1e-5f;

__device__ __forceinline__ float lo16(u32 v) { return __uint_as_float(v << 16); }
__device__ __forceinline__ float hi16(u32 v) { return __uint_as_float(v & 0xFFFF0000u); }
__device__ __forceinline__ u16 bfbits(float f) {
    __hip_bfloat16 h = __float2bfloat16(f);
    return *reinterpret_cast<u16*>(&h);
}

// K0 v2: wt[c][k] split-bf16; c in [0,128) = W cols; [128,136) = attention
// projection cols (W@att_s, W@att_d per head); [136,144) = zero pad.
__global__ __launch_bounds__(256) void k0_wprep(
    const float* __restrict__ W,
    const float* __restrict__ att_s, const float* __restrict__ att_d,
    u16* __restrict__ wt_hi, u16* __restrict__ wt_lo)
{
    const int i = blockIdx.x * 256 + threadIdx.x;   // 72 blocks: 144*128 entries
    if (i >= WT_COLS * 128) return;
    const int c = i >> 7, k = i & 127;
    float w = 0.f;
    if (c < 128) {
        w = W[k * 128 + c];
    } else if (c < 136) {
        const int vc = c - 128;
        const int h = vc & 3;
        const float* att = (vc < 4) ? att_s : att_d;
        float s = 0.f;
#pragma unroll
        for (int j = 0; j < 32; ++j)
            s = fmaf(W[k * 128 + h * 32 + j], att[h * 32 + j], s);
        w = s;
    }
    const __hip_bfloat16 h = __float2bfloat16(w);
    const float fh = __bfloat162float(h);
    wt_hi[i] = *(const u16*)&h;
    wt_lo[i] = bfbits(w - fh);
}

// KG v4.1: B (shared operand, 782x reuse) staged in padded LDS; A (x rows,
// zero reuse) in registers. R13's bug fixed: each 128-u16 wt row is 16
// float4 units, not 8 (cols 64-127 were unstaged -> NaN).
// 64-row blocks, 4 waves; ~100 VGPR; LDS 78.3 KB -> 2 blocks/CU.
// Numerically bit-identical MFMA sequence to R11/R12.
__global__ __launch_bounds__(256, 2) void kg_gemm(
    const float* __restrict__ x,
    const u16* __restrict__ wt_hi, const u16* __restrict__ wt_lo,
    u16* __restrict__ hb, float* __restrict__ as_, float* __restrict__ ad_)
{
    constexpr int LROW = 136;                 // padded row stride in u16
    __shared__ u16 sbh[WT_COLS * LROW];       // 39168 B
    __shared__ u16 sbl[WT_COLS * LROW];       // 39168 B
    const int t    = threadIdx.x;
    const int m0   = (int)blockIdx.x * 64;
    const int lane = t & 63;
    const int w    = t >> 6;                  // wave id: rows [w*16, w*16+16)
    const int bcol = lane & 15;               // A row within slice / B col / C col
    const int akg  = lane >> 4;               // k-group 0..3 / C row quarter

    // issue all 8 x loads (cold HBM) first — they drain during LDS staging
    const int arow = min(m0 + w * 16 + bcol, N - 1);
    const float* xr = x + (size_t)arow * 128 + akg * 8;
    float4 q[8];
#pragma unroll
    for (int ks = 0; ks < 4; ++ks) {
        q[2 * ks]     = *(const float4*)(xr + ks * 32);
        q[2 * ks + 1] = *(const float4*)(xr + ks * 32 + 4);
    }

    // stage wt -> LDS (144 rows x 16 x 16B units each array)
    for (int i = t; i < WT_COLS * 16; i += 256) {
        const int row = i >> 4, c16 = i & 15;
        *(float4*)(sbh + row * LROW + c16 * 8) =
            *(const float4*)(wt_hi + row * 128 + c16 * 8);
        *(float4*)(sbl + row * LROW + c16 * 8) =
            *(const float4*)(wt_lo + row * 128 + c16 * 8);
    }

    // convert x -> A fragments while staging loads are in flight
    bf16x8 Ah[4], Al[4];
#pragma unroll
    for (int ks = 0; ks < 4; ++ks) {
        const float4 qa = q[2 * ks];
        const float4 qb = q[2 * ks + 1];
        const float f[8] = {qa.x, qa.y, qa.z, qa.w, qb.x, qb.y, qb.z, qb.w};
#pragma unroll
        for (int j = 0; j < 8; ++j) {
            const __hip_bfloat16 hh = __float2bfloat16(f[j]);
            Ah[ks][j] = *(const short*)&hh;
            const __hip_bfloat16 hl = __float2bfloat16(f[j] - __bfloat162float(hh));
            Al[ks][j] = *(const short*)&hl;
        }
    }
    __syncthreads();

    f32x4 acc[9];
#pragma unroll
    for (int nt = 0; nt < 9; ++nt) acc[nt] = f32x4{0.f, 0.f, 0.f, 0.f};

    const u16* bh0 = sbh + bcol * LROW + akg * 8;
    const u16* bl0 = sbl + bcol * LROW + akg * 8;
#pragma unroll
    for (int ks = 0; ks < 4; ++ks) {
#pragma unroll
        for (int nt = 0; nt < 9; ++nt) {
            const bf16x8 Bh = *(const bf16x8*)(bh0 + nt * 16 * LROW + ks * 32);
            const bf16x8 Bl = *(const bf16x8*)(bl0 + nt * 16 * LROW + ks * 32);
            acc[nt] = __builtin_amdgcn_mfma_f32_16x16x32_bf16(Ah[ks], Bh, acc[nt], 0, 0, 0);
            acc[nt] = __builtin_amdgcn_mfma_f32_16x16x32_bf16(Al[ks], Bh, acc[nt], 0, 0, 0);
            acc[nt] = __builtin_amdgcn_mfma_f32_16x16x32_bf16(Ah[ks], Bl, acc[nt], 0, 0, 0);
        }
    }

    // hb store: C/D layout col=lane&15, row=(lane>>4)*4+reg  [m89/m91]
#pragma unroll
    for (int nt = 0; nt < 8; ++nt) {
        const int ch = nt * 16 + bcol;
#pragma unroll
        for (int r = 0; r < 4; ++r) {
            const int node = m0 + w * 16 + akg * 4 + r;
            if (node < N) hb[(size_t)node * 128 + ch] = bfbits(acc[nt][r]);
        }
    }

    // attention projections: tile 8 (cols 0-3: as head, 4-7: ad head)
    if (bcol < 8) {
        float* dst = (bcol < 4) ? (as_ + bcol) : (ad_ + (bcol - 4));
#pragma unroll
        for (int r = 0; r < 4; ++r) {
            const int node = m0 + w * 16 + akg * 4 + r;
            if (node < N) dst[(size_t)node * H] = acc[8][r];
        }
    }
}

// KC: per-chunk dst-bucket counts (unchanged — control).
__global__ __launch_bounds__(256) void kc_count(
    const int* __restrict__ ei, u32* __restrict__ gcnt)
{
    __shared__ u32 lcnt[NB];
    const int t = threadIdx.x;
    const int c = blockIdx.x;
    const int base = c * CHUNK;
    for (int i = t; i < NB; i += 256) lcnt[i] = 0;
    __syncthreads();
    for (int i = t; i < CHUNK; i += 256)
        atomicAdd(&lcnt[((u32)ei[E + base + i]) >> 6], 1u);
    __syncthreads();
    for (int i = t; i < NB; i += 256) gcnt[i * NCH + c] = lcnt[i];
}

// S2A (unchanged — control): per-bucket scan over chunks.
__global__ __launch_bounds__(256) void s2a_scan(
    const u32* __restrict__ gcnt, u32* __restrict__ gbase, u32* __restrict__ tot)
{
    __shared__ u32 wsum[4];
    const int b = blockIdx.x, t = threadIdx.x, lane = t & 63, w = t >> 6;
    const u32 v = gcnt[b * NCH + t];
    u32 incl = v;
#pragma unroll
    for (int off = 1; off < 64; off <<= 1) {
        u32 u = __shfl_up(incl, off, 64);
        if (lane >= off) incl += u;
    }
    if (lane == 63) wsum[w] = incl;
    __syncthreads();
    u32 wpre = 0;
#pragma unroll
    for (int i = 0; i < 4; ++i) if (i < w) wpre += wsum[i];
    gbase[b * NCH + t] = wpre + incl - v;
    if (t == 255) tot[b] = wpre + incl;
}

// S2B (unchanged — control): exclusive scan of tot -> bbase.
__global__ __launch_bounds__(64) void s2b_scan(
    const u32* __restrict__ tot, u32* __restrict__ bbase)
{
    const int t = threadIdx.x;
    u32 vals[13];
    u32 s = 0;
#pragma unroll
    for (int i = 0; i < 13; ++i) {
        int idx = t * 13 + i;
        u32 v = (idx < NB) ? tot[idx] : 0u;
        vals[i] = s; s += v;
    }
    u32 incl = s;
#pragma unroll
    for (int off = 1; off < 64; off <<= 1) {
        u32 u = __shfl_up(incl, off, 64);
        if (t >= off) incl += u;
    }
    const u32 excl = incl - s;
#pragma unroll
    for (int i = 0; i < 13; ++i) {
        int idx = t * 13 + i;
        if (idx < NB) bbase[idx] = excl + vals[i];
    }
}

// KBINB v2 (unchanged — control).
__global__ __launch_bounds__(256) void kbinB(
    const int* __restrict__ ei, const u32* __restrict__ gbase,
    const u32* __restrict__ bbase, u32* __restrict__ pairs)
{
    __shared__ u32 sl[NB];
    __shared__ u32 lfill[NB];
    const int t = threadIdx.x;
    const int c = blockIdx.x;

    for (int i = t; i < NB; i += 256) {
        sl[i] = bbase[i] + gbase[(size_t)i * NCH + c];
        lfill[i] = 0u;
    }
    __syncthreads();

    const int base = c * CHUNK;
    for (int i = t; i < CHUNK; i += 256) {
        const u32 src = (u32)ei[base + i];
        const u32 dst = (u32)ei[E + base + i];
        const u32 b = dst >> 6;
        const u32 pos = atomicAdd(&lfill[b], 1u);
        pairs[sl[b] + pos] = src | ((dst & 63u) << 16);
    }
}

// KFILL2 v2 (unchanged — control).
__global__ __launch_bounds__(256) void kfill2(
    const u32* __restrict__ pairs, const u32* __restrict__ tot,
    const u32* __restrict__ bbase, int* __restrict__ row_ptr, u16* __restrict__ col)
{
    __shared__ u32 spr[CAP];
    __shared__ u16 scol[CAP];
    __shared__ int jcnt[64], joff[64], jcur[64];
    const int b = blockIdx.x, t = threadIdx.x;
    const int base = (int)bbase[b];
    const int cntb = (int)tot[b];
    if (t < 64) jcnt[t] = 0;
    __syncthreads();

    const u32* pr = pairs + base;
    for (int i = t; i < cntb; i += 256) spr[i] = pr[i];
    __syncthreads();
    for (int i = t; i < cntb; i += 256) atomicAdd(&jcnt[spr[i] >> 16], 1);
    __syncthreads();
    if (t < 64) {
        int v = jcnt[t], incl = v;
#pragma unroll
        for (int off = 1; off < 64; off <<= 1) {
            int u = __shfl_up(incl, off, 64);
            if (t >= off) incl += u;
        }
        joff[t] = incl - v;
        const int n = b * 64 + t;
        if (n < N) row_ptr[n] = base + joff[t];
        jcur[t] = 0;
    }
    __syncthreads();
    for (int i = t; i < cntb; i += 256) {
        const u32 p = spr[i];
        const int j = p >> 16;
        const int pos = atomicAdd(&jcur[j], 1);
        scol[joff[j] + pos] = (u16)(p & 0xFFFFu);
    }
    __syncthreads();
    for (int i = t; i < cntb; i += 256) col[base + i] = scol[i];
    if (b == 0 && t == 0) row_ptr[N] = E;
}

// KD v4 (unchanged — control), two half-dispatches via n0 offset.
__global__ __launch_bounds__(256) void kd_agg_ln(
    const int* __restrict__ row_ptr, const u16* __restrict__ col,
    const u32* __restrict__ hb, const float* __restrict__ as_,
    const float* __restrict__ ad_,
    const float* __restrict__ bias, const float* __restrict__ gamma,
    const float* __restrict__ beta, float* __restrict__ out, int n0)
{
    __shared__ float wlds[4][64];
    const int tid  = threadIdx.x;
    const int lane = tid & 63;
    const int wv   = __builtin_amdgcn_readfirstlane(tid >> 6);
    const int n    = __builtin_amdgcn_readfirstlane(n0 + (int)blockIdx.x * 4 + (tid >> 6));
    if (n >= N) return;

    const int head  = lane >> 4;
    const int eoff  = lane & 15;
    const int wbase = head << 4;
    float* __restrict__ wrow = wlds[wv];

    const float adn = ad_[n * H + head];
    const float asn = as_[n * H + head];

    float ls = asn + adn;
    ls = fmaxf(ls, NEG * ls);
    const float wself = __expf(ls);
    float den = (eoff == 0) ? wself : 0.f;
    const u32 hvs = hb[n * 64 + lane];
    float num0 = wself * lo16(hvs);
    float num1 = wself * hi16(hvs);

    const int k0  = row_ptr[n];
    const int deg = row_ptr[n + 1] - k0;
    const int ntiles = (deg + 15) >> 4;

    const int cnt0 = deg < 16 ? deg : 16;
    const int cnt1 = (deg - 16) < 16 ? (deg - 16) : 16;
    int colv_cur = (eoff < cnt0) ? (int)col[k0 + eoff]      : 0;
    int colv_nxt = (eoff < cnt1) ? (int)col[k0 + 16 + eoff] : 0;
    float a_cur  = as_[colv_cur * H + head];
    int cntc = cnt0, cntn = cnt1;

    int k = k0;
    for (int t = 0; t < ntiles; ++t, k += 16) {
        const int rem2 = deg - 16 * (t + 2);
        const int cnt2 = rem2 < 16 ? rem2 : 16;
        const int cf_raw = (int)col[k + 32 + eoff];
        const int colv_f = (eoff < cnt2) ? cf_raw : 0;

        float le = a_cur + adn;
        le = fmaxf(le, NEG * le);
        const float w = (eoff < cntc) ? __expf(le) : 0.f;
        den += w;
        wrow[lane] = w;
        const int colc = colv_cur;

#define GL(i) const u32* rp##i = hb + ((size_t)(u32)__builtin_amdgcn_readlane(colc, i) << 6); \
              const u32 v##i = rp##i[lane];
        GL(0) GL(1) GL(2) GL(3) GL(4) GL(5) GL(6) GL(7)
        GL(8) GL(9) GL(10) GL(11) GL(12) GL(13) GL(14) GL(15)
#undef GL
        __builtin_amdgcn_sched_barrier(0);

        const float a_n = as_[colv_nxt * H + head];
        __builtin_amdgcn_sched_barrier(0);

        {
            const float4 wa = *(const float4*)(wrow + wbase + 0);
            num0 = fmaf(wa.x, lo16(v0), num0);  num1 = fmaf(wa.x, hi16(v0), num1);
            num0 = fmaf(wa.y, lo16(v1), num0);  num1 = fmaf(wa.y, hi16(v1), num1);
            num0 = fmaf(wa.z, lo16(v2), num0);  num1 = fmaf(wa.z, hi16(v2), num1);
            num0 = fmaf(wa.w, lo16(v3), num0);  num1 = fmaf(wa.w, hi16(v3), num1);
            const float4 wb = *(const float4*)(wrow + wbase + 4);
            num0 = fmaf(wb.x, lo16(v4), num0);  num1 = fmaf(wb.x, hi16(v4), num1);
            num0 = fmaf(wb.y, lo16(v5), num0);  num1 = fmaf(wb.y, hi16(v5), num1);
            num0 = fmaf(wb.z, lo16(v6), num0);  num1 = fmaf(wb.z, hi16(v6), num1);
            num0 = fmaf(wb.w, lo16(v7), num0);  num1 = fmaf(wb.w, hi16(v7), num1);
            const float4 wc = *(const float4*)(wrow + wbase + 8);
            num0 = fmaf(wc.x, lo16(v8), num0);  num1 = fmaf(wc.x, hi16(v8), num1);
            num0 = fmaf(wc.y, lo16(v9), num0);  num1 = fmaf(wc.y, hi16(v9), num1);
            num0 = fmaf(wc.z, lo16(v10), num0); num1 = fmaf(wc.z, hi16(v10), num1);
            num0 = fmaf(wc.w, lo16(v11), num0); num1 = fmaf(wc.w, hi16(v11), num1);
            const float4 wd = *(const float4*)(wrow + wbase + 12);
            num0 = fmaf(wd.x, lo16(v12), num0); num1 = fmaf(wd.x, hi16(v12), num1);
            num0 = fmaf(wd.y, lo16(v13), num0); num1 = fmaf(wd.y, hi16(v13), num1);
            num0 = fmaf(wd.z, lo16(v14), num0); num1 = fmaf(wd.z, hi16(v14), num1);
            num0 = fmaf(wd.w, lo16(v15), num0); num1 = fmaf(wd.w, hi16(v15), num1);
        }

        colv_cur = colv_nxt; colv_nxt = colv_f;
        a_cur = a_n;
        cntc = cntn; cntn = cnt2;
    }

#pragma unroll
    for (int off = 1; off < 16; off <<= 1) den += __shfl_xor(den, off, 64);

    const int c0 = lane * 2;
    const float inv_den = 1.f / (den + SEPS);
    const float2 bi = *(const float2*)(bias + c0);
    float v0 = num0 * inv_den + bi.x;
    float v1 = num1 * inv_den + bi.y;

    float sum = v0 + v1;
#pragma unroll
    for (int off = 32; off; off >>= 1) sum += __shfl_xor(sum, off, 64);
    const float mu = sum * (1.0f / C);
    const float d0 = v0 - mu, d1 = v1 - mu;
    float sq = d0 * d0 + d1 * d1;
#pragma unroll
    for (int off = 32; off; off >>= 1) sq += __shfl_xor(sq, off, 64);
    const float inv = rsqrtf(sq * (1.0f / C) + LEPS);
    const float2 ga = *(const float2*)(gamma + c0);
    const float2 be = *(const float2*)(beta  + c0);
    float y0 = d0 * inv * ga.x + be.x;
    float y1 = d1 * inv * ga.y + be.y;
    y0 = y0 > 0.f ? y0 : __expf(y0) - 1.f;
    y1 = y1 > 0.f ? y1 : __expf(y1) - 1.f;
    float2 o; o.x = y0; o.y = y1;
    *(float2*)(out + (size_t)n * C + c0) = o;
}

extern "C" void kernel_launch(void* const* d_in, const int* in_sizes, int n_in,
                              void* d_out, int out_size, void* d_ws, size_t ws_size,
                              hipStream_t stream)
{
    const float* x     = (const float*)d_in[0];
    const int*   ei    = (const int*)  d_in[1];
    const float* W     = (const float*)d_in[2];
    const float* att_s = (const float*)d_in[3];
    const float* att_d = (const float*)d_in[4];
    const float* bias  = (const float*)d_in[5];
    const float* gamma = (const float*)d_in[6];
    const float* beta  = (const float*)d_in[7];
    float* out = (float*)d_out;

    // ws (~26 MB): hb | as_ | ad_ | pairs | col | row_ptr | gcnt | gbase
    //            | tot | bbase | wt_hi | wt_lo
    char* p = (char*)d_ws;
    bf16*  hb      = (bf16*)p;   p += (size_t)N * C * sizeof(bf16);
    float* as_     = (float*)p;  p += (size_t)N * H * sizeof(float);
    float* ad_     = (float*)p;  p += (size_t)N * H * sizeof(float);
    u32*   pairs   = (u32*)p;    p += (size_t)E * sizeof(u32);
    u16*   col     = (u16*)p;    p += ((size_t)(E + 64) * sizeof(u16) + 15) & ~(size_t)15;
    int*   row_ptr = (int*)p;    p += ((size_t)(N + 1) * sizeof(int) + 15) & ~(size_t)15;
    u32*   gcnt    = (u32*)p;    p += (size_t)NB * NCH * sizeof(u32);
    u32*   gbase   = (u32*)p;    p += (size_t)NB * NCH * sizeof(u32);
    u32*   tot     = (u32*)p;    p += (((size_t)NB * sizeof(u32)) + 15) & ~(size_t)15;
    u32*   bbase   = (u32*)p;    p += (((size_t)NB * sizeof(u32)) + 15) & ~(size_t)15;
    u16*   wt_hi   = (u16*)p;    p += (size_t)WT_COLS * 128 * sizeof(u16);
    u16*   wt_lo   = (u16*)p;

    k0_wprep<<<(WT_COLS * 128 + 255) / 256, 256, 0, stream>>>(W, att_s, att_d, wt_hi, wt_lo);
    kg_gemm<<<NB, 256, 0, stream>>>(x, wt_hi, wt_lo, (u16*)hb, as_, ad_);
    kc_count<<<NCH, 256, 0, stream>>>(ei, gcnt);
    s2a_scan<<<NB, 256, 0, stream>>>(gcnt, gbase, tot);
    s2b_scan<<<1, 64, 0, stream>>>(tot, bbase);
    kbinB<<<NCH, 256, 0, stream>>>(ei, gbase, bbase, pairs);
    kfill2<<<NB, 256, 0, stream>>>(pairs, tot, bbase, row_ptr, col);
    kd_agg_ln<<<(25000 * 64) / 256, 256, 0, stream>>>(
        row_ptr, col, (const u32*)hb, as_, ad_, bias, gamma, beta, out, 0);
    kd_agg_ln<<<(25000 * 64) / 256, 256, 0, stream>>>(
        row_ptr, col, (const u32*)hb, as_, ad_, bias, gamma, beta, out, 25000);
}

// Round 15
// 203.485 us; speedup vs baseline: 1.1761x; 1.0253x over previous
//
#include <hip/hip_runtime.h>
#include <hip/hip_bf16.h>

typedef __hip_bfloat16 bf16;
typedef unsigned int u32;
typedef unsigned short u16;
typedef __attribute__((ext_vector_type(8))) short bf16x8;
typedef __attribute__((ext_vector_type(4))) float f32x4;

constexpr int N   = 50000;
constexpr int E   = 1600000;
constexpr int C   = 128;             // channels (H * 32)
constexpr int H   = 4;               // heads
constexpr int NB  = 782;             // dst buckets of 64 nodes (782*64 >= 50000)
constexpr int CAP = 2560;            // LDS staging capacity per bucket in kfill2
constexpr int NCH = 256;             // chunks (bin-count blocks)
constexpr int CHUNK = E / NCH;       // 6250 edges per chunk (exact)
constexpr int WT_COLS = 144;         // 128 h-cols + 8 att-proj cols + 8 zero pad
constexpr int GEMM_BLOCKS = 782;     // 782*64 >= 50000 nodes
constexpr float NEG  = 0.2f;
constexpr float SEPS = 1e-16f;
constexpr float LEPS = 1e-5f;

__device__ __forceinline__ float lo16(u32 v) { return __uint_as_float(v << 16); }
__device__ __forceinline__ float hi16(u32 v) { return __uint_as_float(v & 0xFFFF0000u); }
__device__ __forceinline__ u16 bfbits(float f) {
    __hip_bfloat16 h = __float2bfloat16(f);
    return *reinterpret_cast<u16*>(&h);
}

// K0 v2: wt[c][k] split-bf16; c in [0,128) = W cols; [128,136) = attention
// projection cols (W@att_s, W@att_d per head); [136,144) = zero pad.
__global__ __launch_bounds__(256) void k0_wprep(
    const float* __restrict__ W,
    const float* __restrict__ att_s, const float* __restrict__ att_d,
    u16* __restrict__ wt_hi, u16* __restrict__ wt_lo)
{
    const int i = blockIdx.x * 256 + threadIdx.x;   // 72 blocks: 144*128 entries
    if (i >= WT_COLS * 128) return;
    const int c = i >> 7, k = i & 127;
    float w = 0.f;
    if (c < 128) {
        w = W[k * 128 + c];
    } else if (c < 136) {
        const int vc = c - 128;
        const int h = vc & 3;
        const float* att = (vc < 4) ? att_s : att_d;
        float s = 0.f;
#pragma unroll
        for (int j = 0; j < 32; ++j)
            s = fmaf(W[k * 128 + h * 32 + j], att[h * 32 + j], s);
        w = s;
    }
    const __hip_bfloat16 h = __float2bfloat16(w);
    const float fh = __bfloat162float(h);
    wt_hi[i] = *(const u16*)&h;
    wt_lo[i] = bfbits(w - fh);
}

// KG v5: fused GEMM + count (f1 pattern, R5-R9 proven; both branch bodies
// byte-identical to R14's kg / kc).
//   blocks [0,782): MFMA GEMM, B staged in padded LDS (R14-validated).
//   blocks [782,1038): per-chunk dst-bucket counts -> gcnt[b][c].
__global__ __launch_bounds__(256, 2) void kg_gemm_count(
    const float* __restrict__ x,
    const u16* __restrict__ wt_hi, const u16* __restrict__ wt_lo,
    const int* __restrict__ ei,
    u16* __restrict__ hb, float* __restrict__ as_, float* __restrict__ ad_,
    u32* __restrict__ gcnt)
{
    constexpr int LROW = 136;                 // padded row stride in u16
    union Smem {
        struct { u16 sbh[WT_COLS * LROW]; u16 sbl[WT_COLS * LROW]; } g; // 78336 B
        u32 lcnt[NB];                                                    // 3128 B
    };
    __shared__ Smem sm;
    const int t = threadIdx.x;

    if (blockIdx.x >= GEMM_BLOCKS) {
        // ---- bin count branch (byte-identical logic to R14 kc_count) ----
        const int c = blockIdx.x - GEMM_BLOCKS;
        const int base = c * CHUNK;
        for (int i = t; i < NB; i += 256) sm.lcnt[i] = 0;
        __syncthreads();
        for (int i = t; i < CHUNK; i += 256)
            atomicAdd(&sm.lcnt[((u32)ei[E + base + i]) >> 6], 1u);
        __syncthreads();
        for (int i = t; i < NB; i += 256) gcnt[i * NCH + c] = sm.lcnt[i];
        return;
    }

    // ---- GEMM branch (byte-identical logic to R14 kg_gemm) ----
    const int m0   = (int)blockIdx.x * 64;
    const int lane = t & 63;
    const int w    = t >> 6;                  // wave id: rows [w*16, w*16+16)
    const int bcol = lane & 15;               // A row within slice / B col / C col
    const int akg  = lane >> 4;               // k-group 0..3 / C row quarter

    // issue all 8 x loads (cold HBM) first — they drain during LDS staging
    const int arow = min(m0 + w * 16 + bcol, N - 1);
    const float* xr = x + (size_t)arow * 128 + akg * 8;
    float4 q[8];
#pragma unroll
    for (int ks = 0; ks < 4; ++ks) {
        q[2 * ks]     = *(const float4*)(xr + ks * 32);
        q[2 * ks + 1] = *(const float4*)(xr + ks * 32 + 4);
    }

    // stage wt -> LDS (144 rows x 16 x 16B units each array)
    for (int i = t; i < WT_COLS * 16; i += 256) {
        const int row = i >> 4, c16 = i & 15;
        *(float4*)(sm.g.sbh + row * LROW + c16 * 8) =
            *(const float4*)(wt_hi + row * 128 + c16 * 8);
        *(float4*)(sm.g.sbl + row * LROW + c16 * 8) =
            *(const float4*)(wt_lo + row * 128 + c16 * 8);
    }

    // convert x -> A fragments while staging loads are in flight
    bf16x8 Ah[4], Al[4];
#pragma unroll
    for (int ks = 0; ks < 4; ++ks) {
        const float4 qa = q[2 * ks];
        const float4 qb = q[2 * ks + 1];
        const float f[8] = {qa.x, qa.y, qa.z, qa.w, qb.x, qb.y, qb.z, qb.w};
#pragma unroll
        for (int j = 0; j < 8; ++j) {
            const __hip_bfloat16 hh = __float2bfloat16(f[j]);
            Ah[ks][j] = *(const short*)&hh;
            const __hip_bfloat16 hl = __float2bfloat16(f[j] - __bfloat162float(hh));
            Al[ks][j] = *(const short*)&hl;
        }
    }
    __syncthreads();

    f32x4 acc[9];
#pragma unroll
    for (int nt = 0; nt < 9; ++nt) acc[nt] = f32x4{0.f, 0.f, 0.f, 0.f};

    const u16* bh0 = sm.g.sbh + bcol * LROW + akg * 8;
    const u16* bl0 = sm.g.sbl + bcol * LROW + akg * 8;
#pragma unroll
    for (int ks = 0; ks < 4; ++ks) {
#pragma unroll
        for (int nt = 0; nt < 9; ++nt) {
            const bf16x8 Bh = *(const bf16x8*)(bh0 + nt * 16 * LROW + ks * 32);
            const bf16x8 Bl = *(const bf16x8*)(bl0 + nt * 16 * LROW + ks * 32);
            acc[nt] = __builtin_amdgcn_mfma_f32_16x16x32_bf16(Ah[ks], Bh, acc[nt], 0, 0, 0);
            acc[nt] = __builtin_amdgcn_mfma_f32_16x16x32_bf16(Al[ks], Bh, acc[nt], 0, 0, 0);
            acc[nt] = __builtin_amdgcn_mfma_f32_16x16x32_bf16(Ah[ks], Bl, acc[nt], 0, 0, 0);
        }
    }

    // hb store: C/D layout col=lane&15, row=(lane>>4)*4+reg  [m89/m91]
#pragma unroll
    for (int nt = 0; nt < 8; ++nt) {
        const int ch = nt * 16 + bcol;
#pragma unroll
        for (int r = 0; r < 4; ++r) {
            const int node = m0 + w * 16 + akg * 4 + r;
            if (node < N) hb[(size_t)node * 128 + ch] = bfbits(acc[nt][r]);
        }
    }

    // attention projections: tile 8 (cols 0-3: as head, 4-7: ad head)
    if (bcol < 8) {
        float* dst = (bcol < 4) ? (as_ + bcol) : (ad_ + (bcol - 4));
#pragma unroll
        for (int r = 0; r < 4; ++r) {
            const int node = m0 + w * 16 + akg * 4 + r;
            if (node < N) dst[(size_t)node * H] = acc[8][r];
        }
    }
}

// S2A (unchanged — control): per-bucket scan over chunks.
__global__ __launch_bounds__(256) void s2a_scan(
    const u32* __restrict__ gcnt, u32* __restrict__ gbase, u32* __restrict__ tot)
{
    __shared__ u32 wsum[4];
    const int b = blockIdx.x, t = threadIdx.x, lane = t & 63, w = t >> 6;
    const u32 v = gcnt[b * NCH + t];
    u32 incl = v;
#pragma unroll
    for (int off = 1; off < 64; off <<= 1) {
        u32 u = __shfl_up(incl, off, 64);
        if (lane >= off) incl += u;
    }
    if (lane == 63) wsum[w] = incl;
    __syncthreads();
    u32 wpre = 0;
#pragma unroll
    for (int i = 0; i < 4; ++i) if (i < w) wpre += wsum[i];
    gbase[b * NCH + t] = wpre + incl - v;
    if (t == 255) tot[b] = wpre + incl;
}

// S2B (unchanged — control): exclusive scan of tot -> bbase.
__global__ __launch_bounds__(64) void s2b_scan(
    const u32* __restrict__ tot, u32* __restrict__ bbase)
{
    const int t = threadIdx.x;
    u32 vals[13];
    u32 s = 0;
#pragma unroll
    for (int i = 0; i < 13; ++i) {
        int idx = t * 13 + i;
        u32 v = (idx < NB) ? tot[idx] : 0u;
        vals[i] = s; s += v;
    }
    u32 incl = s;
#pragma unroll
    for (int off = 1; off < 64; off <<= 1) {
        u32 u = __shfl_up(incl, off, 64);
        if (t >= off) incl += u;
    }
    const u32 excl = incl - s;
#pragma unroll
    for (int i = 0; i < 13; ++i) {
        int idx = t * 13 + i;
        if (idx < NB) bbase[idx] = excl + vals[i];
    }
}

// KBINB v2 (unchanged — control).
__global__ __launch_bounds__(256) void kbinB(
    const int* __restrict__ ei, const u32* __restrict__ gbase,
    const u32* __restrict__ bbase, u32* __restrict__ pairs)
{
    __shared__ u32 sl[NB];
    __shared__ u32 lfill[NB];
    const int t = threadIdx.x;
    const int c = blockIdx.x;

    for (int i = t; i < NB; i += 256) {
        sl[i] = bbase[i] + gbase[(size_t)i * NCH + c];
        lfill[i] = 0u;
    }
    __syncthreads();

    const int base = c * CHUNK;
    for (int i = t; i < CHUNK; i += 256) {
        const u32 src = (u32)ei[base + i];
        const u32 dst = (u32)ei[E + base + i];
        const u32 b = dst >> 6;
        const u32 pos = atomicAdd(&lfill[b], 1u);
        pairs[sl[b] + pos] = src | ((dst & 63u) << 16);
    }
}

// KFILL2 v2 (unchanged — control).
__global__ __launch_bounds__(256) void kfill2(
    const u32* __restrict__ pairs, const u32* __restrict__ tot,
    const u32* __restrict__ bbase, int* __restrict__ row_ptr, u16* __restrict__ col)
{
    __shared__ u32 spr[CAP];
    __shared__ u16 scol[CAP];
    __shared__ int jcnt[64], joff[64], jcur[64];
    const int b = blockIdx.x, t = threadIdx.x;
    const int base = (int)bbase[b];
    const int cntb = (int)tot[b];
    if (t < 64) jcnt[t] = 0;
    __syncthreads();

    const u32* pr = pairs + base;
    for (int i = t; i < cntb; i += 256) spr[i] = pr[i];
    __syncthreads();
    for (int i = t; i < cntb; i += 256) atomicAdd(&jcnt[spr[i] >> 16], 1);
    __syncthreads();
    if (t < 64) {
        int v = jcnt[t], incl = v;
#pragma unroll
        for (int off = 1; off < 64; off <<= 1) {
            int u = __shfl_up(incl, off, 64);
            if (t >= off) incl += u;
        }
        joff[t] = incl - v;
        const int n = b * 64 + t;
        if (n < N) row_ptr[n] = base + joff[t];
        jcur[t] = 0;
    }
    __syncthreads();
    for (int i = t; i < cntb; i += 256) {
        const u32 p = spr[i];
        const int j = p >> 16;
        const int pos = atomicAdd(&jcur[j], 1);
        scol[joff[j] + pos] = (u16)(p & 0xFFFFu);
    }
    __syncthreads();
    for (int i = t; i < cntb; i += 256) col[base + i] = scol[i];
    if (b == 0 && t == 0) row_ptr[N] = E;
}

// KD v4 (unchanged — control), single dispatch (n0 = 0).
__global__ __launch_bounds__(256) void kd_agg_ln(
    const int* __restrict__ row_ptr, const u16* __restrict__ col,
    const u32* __restrict__ hb, const float* __restrict__ as_,
    const float* __restrict__ ad_,
    const float* __restrict__ bias, const float* __restrict__ gamma,
    const float* __restrict__ beta, float* __restrict__ out, int n0)
{
    __shared__ float wlds[4][64];
    const int tid  = threadIdx.x;
    const int lane = tid & 63;
    const int wv   = __builtin_amdgcn_readfirstlane(tid >> 6);
    const int n    = __builtin_amdgcn_readfirstlane(n0 + (int)blockIdx.x * 4 + (tid >> 6));
    if (n >= N) return;

    const int head  = lane >> 4;
    const int eoff  = lane & 15;
    const int wbase = head << 4;
    float* __restrict__ wrow = wlds[wv];

    const float adn = ad_[n * H + head];
    const float asn = as_[n * H + head];

    float ls = asn + adn;
    ls = fmaxf(ls, NEG * ls);
    const float wself = __expf(ls);
    float den = (eoff == 0) ? wself : 0.f;
    const u32 hvs = hb[n * 64 + lane];
    float num0 = wself * lo16(hvs);
    float num1 = wself * hi16(hvs);

    const int k0  = row_ptr[n];
    const int deg = row_ptr[n + 1] - k0;
    const int ntiles = (deg + 15) >> 4;

    const int cnt0 = deg < 16 ? deg : 16;
    const int cnt1 = (deg - 16) < 16 ? (deg - 16) : 16;
    int colv_cur = (eoff < cnt0) ? (int)col[k0 + eoff]      : 0;
    int colv_nxt = (eoff < cnt1) ? (int)col[k0 + 16 + eoff] : 0;
    float a_cur  = as_[colv_cur * H + head];
    int cntc = cnt0, cntn = cnt1;

    int k = k0;
    for (int t = 0; t < ntiles; ++t, k += 16) {
        const int rem2 = deg - 16 * (t + 2);
        const int cnt2 = rem2 < 16 ? rem2 : 16;
        const int cf_raw = (int)col[k + 32 + eoff];
        const int colv_f = (eoff < cnt2) ? cf_raw : 0;

        float le = a_cur + adn;
        le = fmaxf(le, NEG * le);
        const float w = (eoff < cntc) ? __expf(le) : 0.f;
        den += w;
        wrow[lane] = w;
        const int colc = colv_cur;

#define GL(i) const u32* rp##i = hb + ((size_t)(u32)__builtin_amdgcn_readlane(colc, i) << 6); \
              const u32 v##i = rp##i[lane];
        GL(0) GL(1) GL(2) GL(3) GL(4) GL(5) GL(6) GL(7)
        GL(8) GL(9) GL(10) GL(11) GL(12) GL(13) GL(14) GL(15)
#undef GL
        __builtin_amdgcn_sched_barrier(0);

        const float a_n = as_[colv_nxt * H + head];
        __builtin_amdgcn_sched_barrier(0);

        {
            const float4 wa = *(const float4*)(wrow + wbase + 0);
            num0 = fmaf(wa.x, lo16(v0), num0);  num1 = fmaf(wa.x, hi16(v0), num1);
            num0 = fmaf(wa.y, lo16(v1), num0);  num1 = fmaf(wa.y, hi16(v1), num1);
            num0 = fmaf(wa.z, lo16(v2), num0);  num1 = fmaf(wa.z, hi16(v2), num1);
            num0 = fmaf(wa.w, lo16(v3), num0);  num1 = fmaf(wa.w, hi16(v3), num1);
            const float4 wb = *(const float4*)(wrow + wbase + 4);
            num0 = fmaf(wb.x, lo16(v4), num0);  num1 = fmaf(wb.x, hi16(v4), num1);
            num0 = fmaf(wb.y, lo16(v5), num0);  num1 = fmaf(wb.y, hi16(v5), num1);
            num0 = fmaf(wb.z, lo16(v6), num0);  num1 = fmaf(wb.z, hi16(v6), num1);
            num0 = fmaf(wb.w, lo16(v7), num0);  num1 = fmaf(wb.w, hi16(v7), num1);
            const float4 wc = *(const float4*)(wrow + wbase + 8);
            num0 = fmaf(wc.x, lo16(v8), num0);  num1 = fmaf(wc.x, hi16(v8), num1);
            num0 = fmaf(wc.y, lo16(v9), num0);  num1 = fmaf(wc.y, hi16(v9), num1);
            num0 = fmaf(wc.z, lo16(v10), num0); num1 = fmaf(wc.z, hi16(v10), num1);
            num0 = fmaf(wc.w, lo16(v11), num0); num1 = fmaf(wc.w, hi16(v11), num1);
            const float4 wd = *(const float4*)(wrow + wbase + 12);
            num0 = fmaf(wd.x, lo16(v12), num0); num1 = fmaf(wd.x, hi16(v12), num1);
            num0 = fmaf(wd.y, lo16(v13), num0); num1 = fmaf(wd.y, hi16(v13), num1);
            num0 = fmaf(wd.z, lo16(v14), num0); num1 = fmaf(wd.z, hi16(v14), num1);
            num0 = fmaf(wd.w, lo16(v15), num0); num1 = fmaf(wd.w, hi16(v15), num1);
        }

        colv_cur = colv_nxt; colv_nxt = colv_f;
        a_cur = a_n;
        cntc = cntn; cntn = cnt2;
    }

#pragma unroll
    for (int off = 1; off < 16; off <<= 1) den += __shfl_xor(den, off, 64);

    const int c0 = lane * 2;
    const float inv_den = 1.f / (den + SEPS);
    const float2 bi = *(const float2*)(bias + c0);
    float v0 = num0 * inv_den + bi.x;
    float v1 = num1 * inv_den + bi.y;

    float sum = v0 + v1;
#pragma unroll
    for (int off = 32; off; off >>= 1) sum += __shfl_xor(sum, off, 64);
    const float mu = sum * (1.0f / C);
    const float d0 = v0 - mu, d1 = v1 - mu;
    float sq = d0 * d0 + d1 * d1;
#pragma unroll
    for (int off = 32; off; off >>= 1) sq += __shfl_xor(sq, off, 64);
    const float inv = rsqrtf(sq * (1.0f / C) + LEPS);
    const float2 ga = *(const float2*)(gamma + c0);
    const float2 be = *(const float2*)(beta  + c0);
    float y0 = d0 * inv * ga.x + be.x;
    float y1 = d1 * inv * ga.y + be.y;
    y0 = y0 > 0.f ? y0 : __expf(y0) - 1.f;
    y1 = y1 > 0.f ? y1 : __expf(y1) - 1.f;
    float2 o; o.x = y0; o.y = y1;
    *(float2*)(out + (size_t)n * C + c0) = o;
}

extern "C" void kernel_launch(void* const* d_in, const int* in_sizes, int n_in,
                              void* d_out, int out_size, void* d_ws, size_t ws_size,
                              hipStream_t stream)
{
    const float* x     = (const float*)d_in[0];
    const int*   ei    = (const int*)  d_in[1];
    const float* W     = (const float*)d_in[2];
    const float* att_s = (const float*)d_in[3];
    const float* att_d = (const float*)d_in[4];
    const float* bias  = (const float*)d_in[5];
    const float* gamma = (const float*)d_in[6];
    const float* beta  = (const float*)d_in[7];
    float* out = (float*)d_out;

    // ws (~26 MB): hb | as_ | ad_ | pairs | col | row_ptr | gcnt | gbase
    //            | tot | bbase | wt_hi | wt_lo
    char* p = (char*)d_ws;
    bf16*  hb      = (bf16*)p;   p += (size_t)N * C * sizeof(bf16);
    float* as_     = (float*)p;  p += (size_t)N * H * sizeof(float);
    float* ad_     = (float*)p;  p += (size_t)N * H * sizeof(float);
    u32*   pairs   = (u32*)p;    p += (size_t)E * sizeof(u32);
    u16*   col     = (u16*)p;    p += ((size_t)(E + 64) * sizeof(u16) + 15) & ~(size_t)15;
    int*   row_ptr = (int*)p;    p += ((size_t)(N + 1) * sizeof(int) + 15) & ~(size_t)15;
    u32*   gcnt    = (u32*)p;    p += (size_t)NB * NCH * sizeof(u32);
    u32*   gbase   = (u32*)p;    p += (size_t)NB * NCH * sizeof(u32);
    u32*   tot     = (u32*)p;    p += (((size_t)NB * sizeof(u32)) + 15) & ~(size_t)15;
    u32*   bbase   = (u32*)p;    p += (((size_t)NB * sizeof(u32)) + 15) & ~(size_t)15;
    u16*   wt_hi   = (u16*)p;    p += (size_t)WT_COLS * 128 * sizeof(u16);
    u16*   wt_lo   = (u16*)p;

    k0_wprep<<<(WT_COLS * 128 + 255) / 256, 256, 0, stream>>>(W, att_s, att_d, wt_hi, wt_lo);
    kg_gemm_count<<<GEMM_BLOCKS + NCH, 256, 0, stream>>>(
        x, wt_hi, wt_lo, ei, (u16*)hb, as_, ad_, gcnt);
    s2a_scan<<<NB, 256, 0, stream>>>(gcnt, gbase, tot);
    s2b_scan<<<1, 64, 0, stream>>>(tot, bbase);
    kbinB<<<NCH, 256, 0, stream>>>(ei, gbase, bbase, pairs);
    kfill2<<<NB, 256, 0, stream>>>(pairs, tot, bbase, row_ptr, col);
    kd_agg_ln<<<(N * 64) / 256, 256, 0, stream>>>(
        row_ptr, col, (const u32*)hb, as_, ad_, bias, gamma, beta, out, 0);
}